// Round 8
// baseline (12931.345 us; speedup 1.0000x reference)
//
#include <hip/hip_runtime.h>

#define T_STEPS 64
#define BATCH   128
#define HID     1024
#define VOCAB   10000
#define VPAD    10240
#define NSPLIT  8
#define KCHUNK  256

typedef unsigned short ushort_t;
typedef __attribute__((ext_vector_type(8))) short bf16x8_t;
typedef __attribute__((ext_vector_type(4))) float f32x4_t;

__device__ inline unsigned short f2bf(float f) {
    unsigned int u = __float_as_uint(f);
    u += 0x7fffu + ((u >> 16) & 1u);
    return (unsigned short)(u >> 16);
}

// ---------------------------------------------------------------------------
// init: h0 -> ping buffer 0, h1 -> ping buffer 1 (first reads: layer0 at s=0
// reads buf[0]; layer1 first active at s=1 reads buf[1]).
// ---------------------------------------------------------------------------
__global__ void init_h(const float* __restrict__ hidden,
                       float* __restrict__ h0buf0, float* __restrict__ h1buf1)
{
    int i = blockIdx.x * blockDim.x + threadIdx.x;
    if (i < BATCH * HID) {
        h0buf0[i] = hidden[i];
        h1buf1[i] = hidden[BATCH * HID + i];
    }
}

__global__ void final_h(const float* __restrict__ h0, const float* __restrict__ h1,
                        float* __restrict__ out)
{
    int i = blockIdx.x * blockDim.x + threadIdx.x;
    if (i < BATCH * HID) {
        out[i] = h0[i];
        out[BATCH * HID + i] = h1[i];
    }
}

// ---------------------------------------------------------------------------
// Embedding gather: xemb[row][k] = emb[ids[row]][k]
// ---------------------------------------------------------------------------
__global__ __launch_bounds__(256)
void gather_kernel(const int* __restrict__ ids, const float* __restrict__ emb,
                   float* __restrict__ xemb)
{
    const int row = blockIdx.x;
    const int c4 = threadIdx.x * 4;
    float4 v = *(const float4*)&emb[(size_t)ids[row] * HID + c4];
    *(float4*)&xemb[(size_t)row * HID + c4] = v;
}

// ---------------------------------------------------------------------------
// Wout transpose + bf16: WT[v][k] = bf16(Wout[k][v]); rows >= VOCAB zeroed
// ---------------------------------------------------------------------------
__global__ __launch_bounds__(256)
void woutT_kernel(const float* __restrict__ Wout, ushort_t* __restrict__ WT)
{
    __shared__ float ld[32][33];
    const int v0 = blockIdx.x * 32, k0 = blockIdx.y * 32;
    const int r = threadIdx.x >> 3;
    const int c4 = (threadIdx.x & 7) * 4;
    #pragma unroll
    for (int q = 0; q < 4; ++q) {
        int v = v0 + c4 + q;
        float val = 0.0f;
        if (v < VOCAB) val = Wout[(size_t)(k0 + r) * VOCAB + v];
        ld[c4 + q][r] = val;
    }
    __syncthreads();
    ushort4 o;
    o.x = f2bf(ld[r][c4 + 0]);
    o.y = f2bf(ld[r][c4 + 1]);
    o.z = f2bf(ld[r][c4 + 2]);
    o.w = f2bf(ld[r][c4 + 3]);
    *(ushort4*)&WT[(size_t)(v0 + r) * HID + k0 + c4] = o;
}

// ---------------------------------------------------------------------------
// K1: agemm (round-5 body, verbatim) + fused last-block reduction
//   partial[b,j] = A[b, kchunk] @ W[kchunk, j]  (j in [0,2048): r|z)
//   last block per (layer, jblock): r = tanh(sum+br) -> rmat;
//                                   z = tanh(sum+bz) -> zmat
// grid (32, 8, 2), 256 threads. Accumulation/reduction order == round 5.
// ---------------------------------------------------------------------------
__global__ __launch_bounds__(256)
void agemm_fused(const float* __restrict__ xemb_t0,
                 const float* __restrict__ h0r, const float* __restrict__ h1r,
                 const float* __restrict__ Wr, const float* __restrict__ Wz,
                 const float* __restrict__ br, const float* __restrict__ bz,
                 float* __restrict__ part_rz,
                 float* __restrict__ rmat0, float* __restrict__ rmat1,
                 float* __restrict__ zmat0, float* __restrict__ zmat1,
                 unsigned int* __restrict__ cnt, int s, int do0, int do1)
{
    const int layer = blockIdx.z;
    if (layer == 0 && !do0) return;
    if (layer == 1 && !do1) return;

    __shared__ float As[128][68];
    __shared__ float Bs[64][68];
    const int tid = threadIdx.x;
    const int tx8 = (tid & 7) * 8;
    const int ty  = tid >> 3;
    const int j0 = blockIdx.x * 64;
    const int kbase = blockIdx.y * KCHUNK;

    const float* W = ((j0 < HID) ? Wr : Wz) + (size_t)layer * (2 * HID * HID);
    const int jc = j0 & (HID - 1);
    const float* A_lo = layer ? h0r : xemb_t0;
    const float* A_hi = layer ? h1r : h0r;

    float acc[4][8] = {};

    for (int kt0 = 0; kt0 < KCHUNK; kt0 += 64) {
        const int kt = kbase + kt0;
        #pragma unroll
        for (int i = 0; i < 8; ++i) {
            int f = i * 256 + tid;
            int r = f >> 4;
            int c4 = (f & 15) * 4;
            int kg = kt + c4;
            const float* src = (kg < HID) ? A_lo : A_hi;
            *(float4*)&As[r][c4] =
                *(const float4*)&src[(size_t)r * HID + (kg & (HID - 1))];
        }
        #pragma unroll
        for (int i = 0; i < 4; ++i) {
            int f = i * 256 + tid;
            int r = f >> 4;
            int c4 = (f & 15) * 4;
            *(float4*)&Bs[r][c4] =
                *(const float4*)&W[(size_t)(kt + r) * HID + jc + c4];
        }
        __syncthreads();
        #pragma unroll
        for (int kk4 = 0; kk4 < 64; kk4 += 4) {
            float4 a[4], b0[4], b1[4];
            #pragma unroll
            for (int i = 0; i < 4; ++i)
                a[i] = *(const float4*)&As[ty + i * 32][kk4];
            #pragma unroll
            for (int q = 0; q < 4; ++q) {
                b0[q] = *(const float4*)&Bs[kk4 + q][tx8];
                b1[q] = *(const float4*)&Bs[kk4 + q][tx8 + 4];
            }
            #pragma unroll
            for (int q = 0; q < 4; ++q) {
                #pragma unroll
                for (int i = 0; i < 4; ++i) {
                    acc[i][0] += a[i][q] * b0[q][0];
                    acc[i][1] += a[i][q] * b0[q][1];
                    acc[i][2] += a[i][q] * b0[q][2];
                    acc[i][3] += a[i][q] * b0[q][3];
                    acc[i][4] += a[i][q] * b1[q][0];
                    acc[i][5] += a[i][q] * b1[q][1];
                    acc[i][6] += a[i][q] * b1[q][2];
                    acc[i][7] += a[i][q] * b1[q][3];
                }
            }
        }
        __syncthreads();
    }

    float* dst = part_rz + (size_t)(layer * NSPLIT + blockIdx.y) * (BATCH * 2 * HID);
    #pragma unroll
    for (int i = 0; i < 4; ++i) {
        int b = ty + i * 32;
        float4 v0, v1;
        v0.x = acc[i][0]; v0.y = acc[i][1]; v0.z = acc[i][2]; v0.w = acc[i][3];
        v1.x = acc[i][4]; v1.y = acc[i][5]; v1.z = acc[i][6]; v1.w = acc[i][7];
        *(float4*)&dst[(size_t)b * 2048 + j0 + tx8]     = v0;
        *(float4*)&dst[(size_t)b * 2048 + j0 + tx8 + 4] = v1;
    }

    // ---- last-arriving block reduces this (layer, jblock) ----
    __threadfence();
    __syncthreads();
    __shared__ int lastflag;
    if (tid == 0) {
        unsigned idx = (unsigned)((s * 2 + layer) * 32 + blockIdx.x);
        unsigned old = atomicAdd(&cnt[idx], 1u);
        lastflag = (old == NSPLIT - 1);
    }
    __syncthreads();
    if (!lastflag) return;
    __threadfence();

    const float* pbase = part_rz + (size_t)layer * NSPLIT * (BATCH * 2 * HID);
    float* rm = layer ? rmat1 : rmat0;
    float* zm = layer ? zmat1 : zmat0;
    #pragma unroll
    for (int i = 0; i < 8; ++i) {
        int f = i * 256 + tid;          // 0..2047
        int b = f >> 4;                 // 0..127
        int c4 = (f & 15) * 4;          // 0..60
        int j = j0 + c4;
        const float* p = pbase + (size_t)b * 2048 + j;
        float4 sv = {0.f, 0.f, 0.f, 0.f};
        #pragma unroll
        for (int sp = 0; sp < NSPLIT; ++sp) {
            float4 v = *(const float4*)&p[(size_t)sp * (BATCH * 2 * HID)];
            sv.x += v.x; sv.y += v.y; sv.z += v.z; sv.w += v.w;
        }
        if (j < HID) {
            float4 bb = *(const float4*)&br[layer * HID + j];
            float4 r;
            r.x = tanhf(sv.x + bb.x); r.y = tanhf(sv.y + bb.y);
            r.z = tanhf(sv.z + bb.z); r.w = tanhf(sv.w + bb.w);
            *(float4*)&rm[(size_t)b * HID + j] = r;
        } else {
            float4 bb = *(const float4*)&bz[layer * HID + (j - HID)];
            float4 z;
            z.x = tanhf(sv.x + bb.x); z.y = tanhf(sv.y + bb.y);
            z.z = tanhf(sv.z + bb.z); z.w = tanhf(sv.w + bb.w);
            *(float4*)&zm[(size_t)b * HID + (j - HID)] = z;
        }
    }
}

// ---------------------------------------------------------------------------
// K2: bgemm (round-5 body, verbatim) + fused last-block reduction + h-update
//   A2 (layer0) = k<H ? xemb : r0*h0r ; (layer1) = k<H ? h0r : r1*h1r
//   last block per (layer, jblock): g = tanh(sum+bg);
//     hn = (1-z)*h_old + z*g  -> h ping-pong write; layer1 also h1bf[t1]
// grid (32, 8, 2), 256 threads.
// ---------------------------------------------------------------------------
__global__ __launch_bounds__(256)
void bgemm_fused(const float* __restrict__ xemb_t0,
                 const float* __restrict__ h0r, const float* __restrict__ h1r,
                 float* __restrict__ h0w, float* __restrict__ h1w,
                 const float* __restrict__ rmat0, const float* __restrict__ rmat1,
                 const float* __restrict__ zmat0, const float* __restrict__ zmat1,
                 const float* __restrict__ Wg, const float* __restrict__ bg,
                 float* __restrict__ part_g, ushort_t* __restrict__ h1bf,
                 unsigned int* __restrict__ cnt, int s, int do0, int do1)
{
    const int layer = blockIdx.z;
    if (layer == 0 && !do0) return;
    if (layer == 1 && !do1) return;

    __shared__ float As[128][68];
    __shared__ float Bs[64][36];
    const int tid = threadIdx.x;
    const int tx4 = (tid & 7) * 4;
    const int ty  = tid >> 3;
    const int j0 = blockIdx.x * 32;
    const int kbase = blockIdx.y * KCHUNK;

    const float* W = Wg + (size_t)layer * (2 * HID * HID);
    const float* A_lo = layer ? h0r : xemb_t0;
    const float* A_hi = layer ? h1r : h0r;
    const float* R    = layer ? rmat1 : rmat0;

    float acc[4][4] = {};

    for (int kt0 = 0; kt0 < KCHUNK; kt0 += 64) {
        const int kt = kbase + kt0;
        #pragma unroll
        for (int i = 0; i < 8; ++i) {
            int f = i * 256 + tid;
            int r = f >> 4;
            int c4 = (f & 15) * 4;
            int kg = kt + c4;
            int km = kg & (HID - 1);
            float4 v;
            if (kg < HID) {
                v = *(const float4*)&A_lo[(size_t)r * HID + km];
            } else {
                float4 rv = *(const float4*)&R[(size_t)r * HID + km];
                float4 hv = *(const float4*)&A_hi[(size_t)r * HID + km];
                v.x = rv.x * hv.x; v.y = rv.y * hv.y;
                v.z = rv.z * hv.z; v.w = rv.w * hv.w;
            }
            *(float4*)&As[r][c4] = v;
        }
        #pragma unroll
        for (int i = 0; i < 2; ++i) {
            int f = i * 256 + tid;
            int r = f >> 3;
            int c4 = (f & 7) * 4;
            *(float4*)&Bs[r][c4] =
                *(const float4*)&W[(size_t)(kt + r) * HID + j0 + c4];
        }
        __syncthreads();
        #pragma unroll
        for (int kk4 = 0; kk4 < 64; kk4 += 4) {
            float4 a[4], b[4];
            #pragma unroll
            for (int i = 0; i < 4; ++i)
                a[i] = *(const float4*)&As[ty + i * 32][kk4];
            #pragma unroll
            for (int q = 0; q < 4; ++q)
                b[q] = *(const float4*)&Bs[kk4 + q][tx4];
            #pragma unroll
            for (int q = 0; q < 4; ++q) {
                #pragma unroll
                for (int i = 0; i < 4; ++i) {
                    acc[i][0] += a[i][q] * b[q].x;
                    acc[i][1] += a[i][q] * b[q].y;
                    acc[i][2] += a[i][q] * b[q].z;
                    acc[i][3] += a[i][q] * b[q].w;
                }
            }
        }
        __syncthreads();
    }

    float* dst = part_g + (size_t)(layer * NSPLIT + blockIdx.y) * (BATCH * HID);
    #pragma unroll
    for (int i = 0; i < 4; ++i) {
        int b = ty + i * 32;
        float4 v;
        v.x = acc[i][0]; v.y = acc[i][1]; v.z = acc[i][2]; v.w = acc[i][3];
        *(float4*)&dst[(size_t)b * HID + j0 + tx4] = v;
    }

    // ---- last-arriving block reduces + updates h ----
    __threadfence();
    __syncthreads();
    __shared__ int lastflag;
    if (tid == 0) {
        unsigned idx = (unsigned)((s * 2 + layer) * 32 + blockIdx.x);
        unsigned old = atomicAdd(&cnt[idx], 1u);
        lastflag = (old == NSPLIT - 1);
    }
    __syncthreads();
    if (!lastflag) return;
    __threadfence();

    const float* pbase = part_g + (size_t)layer * NSPLIT * (BATCH * HID);
    const float* zm = layer ? zmat1 : zmat0;
    const float* hr = layer ? h1r : h0r;
    float* hw = layer ? h1w : h0w;
    const int t1 = s - 1;
    #pragma unroll
    for (int i = 0; i < 4; ++i) {
        int f = i * 256 + tid;          // 0..1023
        int b = f >> 3;                 // 0..127
        int c4 = (f & 7) * 4;           // 0..28
        int j = j0 + c4;
        const float* p = pbase + (size_t)b * HID + j;
        float4 sg = {0.f, 0.f, 0.f, 0.f};
        #pragma unroll
        for (int sp = 0; sp < NSPLIT; ++sp) {
            float4 v = *(const float4*)&p[(size_t)sp * (BATCH * HID)];
            sg.x += v.x; sg.y += v.y; sg.z += v.z; sg.w += v.w;
        }
        float4 bgv = *(const float4*)&bg[layer * HID + j];
        float4 g;
        g.x = tanhf(sg.x + bgv.x); g.y = tanhf(sg.y + bgv.y);
        g.z = tanhf(sg.z + bgv.z); g.w = tanhf(sg.w + bgv.w);

        float4 z = *(const float4*)&zm[(size_t)b * HID + j];
        float4 hv = *(const float4*)&hr[(size_t)b * HID + j];
        float4 hn;
        hn.x = (1.0f - z.x) * hv.x + z.x * g.x;
        hn.y = (1.0f - z.y) * hv.y + z.y * g.y;
        hn.z = (1.0f - z.z) * hv.z + z.z * g.z;
        hn.w = (1.0f - z.w) * hv.w + z.w * g.w;
        *(float4*)&hw[(size_t)b * HID + j] = hn;

        if (layer == 1) {
            ushort4 o;
            o.x = f2bf(hn.x); o.y = f2bf(hn.y); o.z = f2bf(hn.z); o.w = f2bf(hn.w);
            *(ushort4*)&h1bf[(size_t)t1 * (BATCH * HID) + (size_t)b * HID + j] = o;
        }
    }
}

// ---------------------------------------------------------------------------
// Logits MFMA GEMM (unchanged): out[i,v] = tanh(h1bf[i,:] @ WT[v,:] + bout[v])
// ---------------------------------------------------------------------------
typedef const unsigned int __attribute__((address_space(1)))* gptr1_t;
typedef unsigned int __attribute__((address_space(3)))* lptr3_t;

__global__ __launch_bounds__(256)
void logits_mfma_kernel(const ushort_t* __restrict__ Abf,
                        const ushort_t* __restrict__ BT,
                        const float* __restrict__ bout,
                        float* __restrict__ out)
{
    __shared__ ushort_t As[128 * 64];
    __shared__ ushort_t Bs[128 * 64];
    const int tid = threadIdx.x;
    const int wave = tid >> 6, lane = tid & 63;
    const int m0 = blockIdx.y * 128, n0 = blockIdx.x * 128;
    const int wr = wave >> 1, wc = wave & 1;

    const int srow = lane >> 3;
    const int sch = (lane & 7) ^ (srow & 7);
    const int lrow = lane & 15, lhi = lane >> 4;

    f32x4_t acc[4][4] = {};

    for (int k0 = 0; k0 < HID; k0 += 64) {
        #pragma unroll
        for (int i = 0; i < 4; ++i) {
            int issue = wave * 4 + i;
            int row = issue * 8 + srow;
            const ushort_t* ga = Abf + (size_t)(m0 + row) * HID + k0 + sch * 8;
            const ushort_t* gb = BT + (size_t)(n0 + row) * HID + k0 + sch * 8;
#if defined(__has_builtin) && __has_builtin(__builtin_amdgcn_global_load_lds)
            __builtin_amdgcn_global_load_lds((gptr1_t)(const void*)ga,
                                             (lptr3_t)(void*)(As + issue * 512), 16, 0, 0);
            __builtin_amdgcn_global_load_lds((gptr1_t)(const void*)gb,
                                             (lptr3_t)(void*)(Bs + issue * 512), 16, 0, 0);
#else
            *(bf16x8_t*)(As + issue * 512 + lane * 8) = *(const bf16x8_t*)ga;
            *(bf16x8_t*)(Bs + issue * 512 + lane * 8) = *(const bf16x8_t*)gb;
#endif
        }
        __syncthreads();

        bf16x8_t af[4][2], bfm[4][2];
        const char* Ab = (const char*)As;
        const char* Bb = (const char*)Bs;
        #pragma unroll
        for (int m = 0; m < 4; ++m) {
            int row = wr * 64 + m * 16 + lrow;
            #pragma unroll
            for (int ks = 0; ks < 2; ++ks) {
                int off = row * 128 + (((ks * 4 + lhi) ^ (lrow & 7)) * 16);
                af[m][ks] = *(const bf16x8_t*)(Ab + off);
            }
        }
        #pragma unroll
        for (int n = 0; n < 4; ++n) {
            int row = wc * 64 + n * 16 + lrow;
            #pragma unroll
            for (int ks = 0; ks < 2; ++ks) {
                int off = row * 128 + (((ks * 4 + lhi) ^ (lrow & 7)) * 16);
                bfm[n][ks] = *(const bf16x8_t*)(Bb + off);
            }
        }
        #pragma unroll
        for (int m = 0; m < 4; ++m)
            #pragma unroll
            for (int n = 0; n < 4; ++n)
                #pragma unroll
                for (int ks = 0; ks < 2; ++ks)
                    acc[m][n] = __builtin_amdgcn_mfma_f32_16x16x32_bf16(
                        af[m][ks], bfm[n][ks], acc[m][n], 0, 0, 0);
        __syncthreads();
    }

    #pragma unroll
    for (int m = 0; m < 4; ++m) {
        int row = m0 + wr * 64 + m * 16 + lhi * 4;
        #pragma unroll
        for (int n = 0; n < 4; ++n) {
            int col = n0 + wc * 64 + n * 16 + lrow;
            if (col < VOCAB) {
                float bo = bout[col];
                #pragma unroll
                for (int q = 0; q < 4; ++q)
                    out[(size_t)(row + q) * VOCAB + col] = tanhf(acc[m][n][q] + bo);
            }
        }
    }
}

// ---------------------------------------------------------------------------
extern "C" void kernel_launch(void* const* d_in, const int* in_sizes, int n_in,
                              void* d_out, int out_size, void* d_ws, size_t ws_size,
                              hipStream_t stream)
{
    const int*   inputs = (const int*)  d_in[0];
    const float* hidden = (const float*)d_in[1];
    const float* emb    = (const float*)d_in[2];
    const float* Wr     = (const float*)d_in[3];
    const float* br     = (const float*)d_in[4];
    const float* Wz     = (const float*)d_in[5];
    const float* bz     = (const float*)d_in[6];
    const float* Wg     = (const float*)d_in[7];
    const float* bg     = (const float*)d_in[8];
    const float* Wout   = (const float*)d_in[9];
    const float* bout   = (const float*)d_in[10];
    float* out = (float*)d_out;

    const size_t BH = BATCH * HID;                 // 131072

    float* ws = (float*)d_ws;
    float* h0buf[2] = { ws,          ws + BH };
    float* h1buf[2] = { ws + 2 * BH, ws + 3 * BH };
    float* rmat0   = ws + 4 * BH;
    float* rmat1   = rmat0 + BH;
    float* zmat0   = rmat1 + BH;
    float* zmat1   = zmat0 + BH;
    float* part_rz = zmat1 + BH;                                 // 2*8*262144
    float* part_g  = part_rz + 2 * NSPLIT * (BATCH * 2 * HID);   // 2*8*131072
    float* xemb    = part_g + 2 * NSPLIT * (BATCH * HID);        // T*B*H
    ushort_t* h1bf = (ushort_t*)(xemb + (size_t)T_STEPS * BH);   // T*B*H bf16
    ushort_t* WT   = h1bf + (size_t)T_STEPS * BH;                // VPAD*H bf16
    unsigned int* cnt1 = (unsigned int*)(WT + (size_t)VPAD * HID);
    unsigned int* cnt2 = cnt1 + (T_STEPS + 1) * 2 * 32;

    // zero the completion counters (capturable memset node)
    hipMemsetAsync(cnt1, 0, 2 * (T_STEPS + 1) * 2 * 32 * sizeof(unsigned int),
                   stream);

    init_h<<<(int)(BH + 255) / 256, 256, 0, stream>>>(hidden, h0buf[0], h1buf[1]);
    gather_kernel<<<T_STEPS * BATCH, 256, 0, stream>>>(inputs, emb, xemb);
    woutT_kernel<<<dim3(VPAD / 32, HID / 32), 256, 0, stream>>>(Wout, WT);

    for (int s = 0; s <= T_STEPS; ++s) {
        int do0 = (s < T_STEPS) ? 1 : 0;
        int do1 = (s >= 1) ? 1 : 0;
        const float* xemb_t0 = xemb + (size_t)s * BH;
        float* h0r = h0buf[s & 1];
        float* h0w = h0buf[(s + 1) & 1];
        float* h1r = h1buf[s & 1];
        float* h1w = h1buf[(s + 1) & 1];

        agemm_fused<<<dim3(32, NSPLIT, 2), 256, 0, stream>>>(
            xemb_t0, h0r, h1r, Wr, Wz, br, bz,
            part_rz, rmat0, rmat1, zmat0, zmat1, cnt1, s, do0, do1);

        bgemm_fused<<<dim3(32, NSPLIT, 2), 256, 0, stream>>>(
            xemb_t0, h0r, h1r, h0w, h1w, rmat0, rmat1, zmat0, zmat1,
            Wg, bg, part_g, h1bf, cnt2, s, do0, do1);
    }

    // layer0 last written at s=63 -> buf[(63+1)&1]=buf[0];
    // layer1 last written at s=64 -> buf[(64+1)&1]=buf[1]
    final_h<<<(int)(BH + 255) / 256, 256, 0, stream>>>(
        h0buf[0], h1buf[1], out + (size_t)T_STEPS * BATCH * VOCAB);

    logits_mfma_kernel<<<dim3(VPAD / 128, 8192 / 128), 256, 0, stream>>>(
        h1bf, WT, bout, out);
}

// Round 9
// 6874.419 us; speedup vs baseline: 1.8811x; 1.8811x over previous
//
#include <hip/hip_runtime.h>

#define T_STEPS 64
#define BATCH   128
#define HID     1024
#define VOCAB   10000
#define VPAD    10240
#define NSPLIT  8
#define KCHUNK  256

typedef unsigned short ushort_t;
typedef __attribute__((ext_vector_type(8))) short bf16x8_t;
typedef __attribute__((ext_vector_type(4))) float f32x4_t;

__device__ inline unsigned short f2bf(float f) {
    unsigned int u = __float_as_uint(f);
    u += 0x7fffu + ((u >> 16) & 1u);
    return (unsigned short)(u >> 16);
}

// ---------------------------------------------------------------------------
__global__ void init_h(const float* __restrict__ hidden,
                       float* __restrict__ h0, float* __restrict__ h1)
{
    int i = blockIdx.x * blockDim.x + threadIdx.x;
    if (i < BATCH * HID) {
        h0[i] = hidden[i];
        h1[i] = hidden[BATCH * HID + i];
    }
}

__global__ void final_h(const float* __restrict__ h0, const float* __restrict__ h1,
                        float* __restrict__ out)
{
    int i = blockIdx.x * blockDim.x + threadIdx.x;
    if (i < BATCH * HID) {
        out[i] = h0[i];
        out[BATCH * HID + i] = h1[i];
    }
}

__global__ __launch_bounds__(256)
void gather_kernel(const int* __restrict__ ids, const float* __restrict__ emb,
                   float* __restrict__ xemb)
{
    const int row = blockIdx.x;
    const int c4 = threadIdx.x * 4;
    float4 v = *(const float4*)&emb[(size_t)ids[row] * HID + c4];
    *(float4*)&xemb[(size_t)row * HID + c4] = v;
}

__global__ __launch_bounds__(256)
void woutT_kernel(const float* __restrict__ Wout, ushort_t* __restrict__ WT)
{
    __shared__ float ld[32][33];
    const int v0 = blockIdx.x * 32, k0 = blockIdx.y * 32;
    const int r = threadIdx.x >> 3;
    const int c4 = (threadIdx.x & 7) * 4;
    #pragma unroll
    for (int q = 0; q < 4; ++q) {
        int v = v0 + c4 + q;
        float val = 0.0f;
        if (v < VOCAB) val = Wout[(size_t)(k0 + r) * VOCAB + v];
        ld[c4 + q][r] = val;
    }
    __syncthreads();
    ushort4 o;
    o.x = f2bf(ld[r][c4 + 0]);
    o.y = f2bf(ld[r][c4 + 1]);
    o.z = f2bf(ld[r][c4 + 2]);
    o.w = f2bf(ld[r][c4 + 3]);
    *(ushort4*)&WT[(size_t)(v0 + r) * HID + k0 + c4] = o;
}

// ---------------------------------------------------------------------------
// agemm_s: scalar-B rz partial GEMM. 512 threads = 8 waves.
// Wave w: rowhalf = w&1 (64 rows, lane = row), colgroup = w>>1 (8 cols).
// Block tile: 128 rows x 32 cols, K = KCHUNK (split blockIdx.y).
// A in LDS [128][68] (bank-uniform for 64-distinct-row b128 reads);
// B via wave-uniform loads -> s_load (SGPR broadcast), no LDS.
// FMA order per output: k ascending (canary-preserving).
// grid (64, 8, 2), 512 threads.
// ---------------------------------------------------------------------------
__global__ __launch_bounds__(512)
void agemm_s(const float* __restrict__ xemb_t0,
             const float* __restrict__ h0, const float* __restrict__ h1,
             const float* __restrict__ Wr, const float* __restrict__ Wz,
             float* __restrict__ part_rz, int do0, int do1)
{
    const int layer = blockIdx.z;
    if (layer == 0 && !do0) return;
    if (layer == 1 && !do1) return;

    __shared__ float As[128][68];
    const int tid = threadIdx.x;
    const int wuni = __builtin_amdgcn_readfirstlane(tid >> 6);  // 0..7 uniform
    const int lane = tid & 63;
    const int row  = (wuni & 1) * 64 + lane;          // 0..127
    const int colb = (wuni >> 1) * 8;                 // 0,8,16,24 (uniform)
    const int j0 = blockIdx.x * 32;                   // 0..2047
    const int kbase = blockIdx.y * KCHUNK;

    const float* W = ((j0 < HID) ? Wr : Wz) + (size_t)layer * (2 * HID * HID);
    const int jc = j0 & (HID - 1);
    const float* A_lo = layer ? h0 : xemb_t0;
    const float* A_hi = layer ? h1 : h0;

    float acc[8] = {};

    for (int kt0 = 0; kt0 < KCHUNK; kt0 += 64) {
        const int ktg = kbase + kt0;
        // stage A row-major [128][64]: 2048 float4, 4 per thread
        #pragma unroll
        for (int i = 0; i < 4; ++i) {
            int f = i * 512 + tid;
            int r = f >> 4;
            int c4 = (f & 15) * 4;
            int kg = ktg + c4;
            const float* src = (kg < HID) ? A_lo : A_hi;
            *(float4*)&As[r][c4] =
                *(const float4*)&src[(size_t)r * HID + (kg & (HID - 1))];
        }
        __syncthreads();
        // compute: per lane 1 row x 8 cols; B wave-uniform (s_load)
        #pragma unroll
        for (int c = 0; c < 16; ++c) {
            f32x4_t a4 = *(const f32x4_t*)&As[row][c * 4];
            #pragma unroll
            for (int q = 0; q < 4; ++q) {
                const float* __restrict__ wk =
                    W + (size_t)(ktg + c * 4 + q) * HID + jc + colb;
                #pragma unroll
                for (int cc = 0; cc < 8; ++cc)
                    acc[cc] += a4[q] * wk[cc];
            }
        }
        __syncthreads();
    }

    // epilogue: transpose through LDS for coalesced stores
    float (*As33)[33] = (float(*)[33])As;
    #pragma unroll
    for (int cc = 0; cc < 8; ++cc)
        As33[row][colb + cc] = acc[cc];
    __syncthreads();

    float* dst = part_rz + (size_t)(layer * NSPLIT + blockIdx.y) * (BATCH * 2 * HID);
    #pragma unroll
    for (int i = 0; i < 2; ++i) {
        int e = i * 512 + tid;        // 0..1023
        int r = e >> 3;               // 0..127
        int c4 = (e & 7) * 4;         // 0..28
        float4 v;
        v.x = As33[r][c4 + 0]; v.y = As33[r][c4 + 1];
        v.z = As33[r][c4 + 2]; v.w = As33[r][c4 + 3];
        *(float4*)&dst[(size_t)r * 2048 + j0 + c4] = v;
    }
}

// ---------------------------------------------------------------------------
// aact: r = tanh(sum_splits part_rz[.., j<H] + br)   (round-5, unchanged)
// ---------------------------------------------------------------------------
__global__ __launch_bounds__(256)
void aact_kernel(const float* __restrict__ part_rz,
                 const float* __restrict__ br,
                 float* __restrict__ rmat0, float* __restrict__ rmat1,
                 int do0, int do1)
{
    const int layer = blockIdx.y;
    if (layer == 0 && !do0) return;
    if (layer == 1 && !do1) return;
    const int idx4 = (blockIdx.x * 256 + threadIdx.x) * 4;
    const int b = idx4 >> 10, j = idx4 & (HID - 1);
    const float* p = part_rz + (size_t)layer * NSPLIT * (BATCH * 2 * HID)
                   + (size_t)b * 2048 + j;
    float4 s = {0.f, 0.f, 0.f, 0.f};
    #pragma unroll
    for (int sp = 0; sp < NSPLIT; ++sp) {
        float4 v = *(const float4*)&p[(size_t)sp * (BATCH * 2 * HID)];
        s.x += v.x; s.y += v.y; s.z += v.z; s.w += v.w;
    }
    float4 bb = *(const float4*)&br[layer * HID + j];
    float4 r;
    r.x = tanhf(s.x + bb.x); r.y = tanhf(s.y + bb.y);
    r.z = tanhf(s.z + bb.z); r.w = tanhf(s.w + bb.w);
    *(float4*)&(layer ? rmat1 : rmat0)[idx4] = r;
}

// ---------------------------------------------------------------------------
// bgemm_s: scalar-B g partial GEMM, same structure as agemm_s.
//   A2 (layer0) = k<H ? xemb : r0*h0 ; (layer1) = k<H ? h0 : r1*h1
// Block tile 128 x 32, grid (32, 8, 2), 512 threads.
// ---------------------------------------------------------------------------
__global__ __launch_bounds__(512)
void bgemm_s(const float* __restrict__ xemb_t0,
             const float* __restrict__ h0, const float* __restrict__ h1,
             const float* __restrict__ rmat0, const float* __restrict__ rmat1,
             const float* __restrict__ Wg,
             float* __restrict__ part_g, int do0, int do1)
{
    const int layer = blockIdx.z;
    if (layer == 0 && !do0) return;
    if (layer == 1 && !do1) return;

    __shared__ float As[128][68];
    const int tid = threadIdx.x;
    const int wuni = __builtin_amdgcn_readfirstlane(tid >> 6);
    const int lane = tid & 63;
    const int row  = (wuni & 1) * 64 + lane;
    const int colb = (wuni >> 1) * 8;
    const int j0 = blockIdx.x * 32;                   // 0..1023
    const int kbase = blockIdx.y * KCHUNK;

    const float* W = Wg + (size_t)layer * (2 * HID * HID);
    const float* A_lo = layer ? h0 : xemb_t0;
    const float* A_hi = layer ? h1 : h0;
    const float* R    = layer ? rmat1 : rmat0;

    float acc[8] = {};

    for (int kt0 = 0; kt0 < KCHUNK; kt0 += 64) {
        const int ktg = kbase + kt0;
        #pragma unroll
        for (int i = 0; i < 4; ++i) {
            int f = i * 512 + tid;
            int r = f >> 4;
            int c4 = (f & 15) * 4;
            int kg = ktg + c4;
            int km = kg & (HID - 1);
            float4 v;
            if (kg < HID) {
                v = *(const float4*)&A_lo[(size_t)r * HID + km];
            } else {
                float4 rv = *(const float4*)&R[(size_t)r * HID + km];
                float4 hv = *(const float4*)&A_hi[(size_t)r * HID + km];
                v.x = rv.x * hv.x; v.y = rv.y * hv.y;
                v.z = rv.z * hv.z; v.w = rv.w * hv.w;
            }
            *(float4*)&As[r][c4] = v;
        }
        __syncthreads();
        #pragma unroll
        for (int c = 0; c < 16; ++c) {
            f32x4_t a4 = *(const f32x4_t*)&As[row][c * 4];
            #pragma unroll
            for (int q = 0; q < 4; ++q) {
                const float* __restrict__ wk =
                    W + (size_t)(ktg + c * 4 + q) * HID + j0 + colb;
                #pragma unroll
                for (int cc = 0; cc < 8; ++cc)
                    acc[cc] += a4[q] * wk[cc];
            }
        }
        __syncthreads();
    }

    float (*As33)[33] = (float(*)[33])As;
    #pragma unroll
    for (int cc = 0; cc < 8; ++cc)
        As33[row][colb + cc] = acc[cc];
    __syncthreads();

    float* dst = part_g + (size_t)(layer * NSPLIT + blockIdx.y) * (BATCH * HID);
    #pragma unroll
    for (int i = 0; i < 2; ++i) {
        int e = i * 512 + tid;
        int r = e >> 3;
        int c4 = (e & 7) * 4;
        float4 v;
        v.x = As33[r][c4 + 0]; v.y = As33[r][c4 + 1];
        v.z = As33[r][c4 + 2]; v.w = As33[r][c4 + 3];
        *(float4*)&dst[(size_t)r * HID + j0 + c4] = v;
    }
}

// ---------------------------------------------------------------------------
// bact: z/g reduction + tanh + h update (round-5, unchanged)
// ---------------------------------------------------------------------------
__global__ __launch_bounds__(256)
void bact_kernel(const float* __restrict__ part_rz, const float* __restrict__ part_g,
                 const float* __restrict__ bz, const float* __restrict__ bg,
                 float* __restrict__ h0, float* __restrict__ h1,
                 ushort_t* __restrict__ h1bf, int t1, int do0, int do1)
{
    const int layer = blockIdx.y;
    if (layer == 0 && !do0) return;
    if (layer == 1 && !do1) return;
    const int idx4 = (blockIdx.x * 256 + threadIdx.x) * 4;
    const int b = idx4 >> 10, j = idx4 & (HID - 1);

    const float* pz = part_rz + (size_t)layer * NSPLIT * (BATCH * 2 * HID)
                    + (size_t)b * 2048 + HID + j;
    float4 sz = {0.f, 0.f, 0.f, 0.f};
    #pragma unroll
    for (int sp = 0; sp < NSPLIT; ++sp) {
        float4 v = *(const float4*)&pz[(size_t)sp * (BATCH * 2 * HID)];
        sz.x += v.x; sz.y += v.y; sz.z += v.z; sz.w += v.w;
    }
    float4 bzv = *(const float4*)&bz[layer * HID + j];
    float4 z;
    z.x = tanhf(sz.x + bzv.x); z.y = tanhf(sz.y + bzv.y);
    z.z = tanhf(sz.z + bzv.z); z.w = tanhf(sz.w + bzv.w);

    const float* pg = part_g + (size_t)layer * NSPLIT * (BATCH * HID) + idx4;
    float4 sg = {0.f, 0.f, 0.f, 0.f};
    #pragma unroll
    for (int sp = 0; sp < NSPLIT; ++sp) {
        float4 v = *(const float4*)&pg[(size_t)sp * (BATCH * HID)];
        sg.x += v.x; sg.y += v.y; sg.z += v.z; sg.w += v.w;
    }
    float4 bgv = *(const float4*)&bg[layer * HID + j];
    float4 g;
    g.x = tanhf(sg.x + bgv.x); g.y = tanhf(sg.y + bgv.y);
    g.z = tanhf(sg.z + bgv.z); g.w = tanhf(sg.w + bgv.w);

    float* h = layer ? h1 : h0;
    float4 hv = *(const float4*)&h[idx4];
    float4 hn;
    hn.x = (1.0f - z.x) * hv.x + z.x * g.x;
    hn.y = (1.0f - z.y) * hv.y + z.y * g.y;
    hn.z = (1.0f - z.z) * hv.z + z.z * g.z;
    hn.w = (1.0f - z.w) * hv.w + z.w * g.w;
    *(float4*)&h[idx4] = hn;

    if (layer == 1) {
        ushort4 o;
        o.x = f2bf(hn.x); o.y = f2bf(hn.y); o.z = f2bf(hn.z); o.w = f2bf(hn.w);
        *(ushort4*)&h1bf[(size_t)t1 * (BATCH * HID) + idx4] = o;
    }
}

// ---------------------------------------------------------------------------
// Logits MFMA GEMM (unchanged)
// ---------------------------------------------------------------------------
typedef const unsigned int __attribute__((address_space(1)))* gptr1_t;
typedef unsigned int __attribute__((address_space(3)))* lptr3_t;

__global__ __launch_bounds__(256)
void logits_mfma_kernel(const ushort_t* __restrict__ Abf,
                        const ushort_t* __restrict__ BT,
                        const float* __restrict__ bout,
                        float* __restrict__ out)
{
    __shared__ ushort_t As[128 * 64];
    __shared__ ushort_t Bs[128 * 64];
    const int tid = threadIdx.x;
    const int wave = tid >> 6, lane = tid & 63;
    const int m0 = blockIdx.y * 128, n0 = blockIdx.x * 128;
    const int wr = wave >> 1, wc = wave & 1;

    const int srow = lane >> 3;
    const int sch = (lane & 7) ^ (srow & 7);
    const int lrow = lane & 15, lhi = lane >> 4;

    f32x4_t acc[4][4] = {};

    for (int k0 = 0; k0 < HID; k0 += 64) {
        #pragma unroll
        for (int i = 0; i < 4; ++i) {
            int issue = wave * 4 + i;
            int row = issue * 8 + srow;
            const ushort_t* ga = Abf + (size_t)(m0 + row) * HID + k0 + sch * 8;
            const ushort_t* gb = BT + (size_t)(n0 + row) * HID + k0 + sch * 8;
#if defined(__has_builtin) && __has_builtin(__builtin_amdgcn_global_load_lds)
            __builtin_amdgcn_global_load_lds((gptr1_t)(const void*)ga,
                                             (lptr3_t)(void*)(As + issue * 512), 16, 0, 0);
            __builtin_amdgcn_global_load_lds((gptr1_t)(const void*)gb,
                                             (lptr3_t)(void*)(Bs + issue * 512), 16, 0, 0);
#else
            *(bf16x8_t*)(As + issue * 512 + lane * 8) = *(const bf16x8_t*)ga;
            *(bf16x8_t*)(Bs + issue * 512 + lane * 8) = *(const bf16x8_t*)gb;
#endif
        }
        __syncthreads();

        bf16x8_t af[4][2], bfm[4][2];
        const char* Ab = (const char*)As;
        const char* Bb = (const char*)Bs;
        #pragma unroll
        for (int m = 0; m < 4; ++m) {
            int row = wr * 64 + m * 16 + lrow;
            #pragma unroll
            for (int ks = 0; ks < 2; ++ks) {
                int off = row * 128 + (((ks * 4 + lhi) ^ (lrow & 7)) * 16);
                af[m][ks] = *(const bf16x8_t*)(Ab + off);
            }
        }
        #pragma unroll
        for (int n = 0; n < 4; ++n) {
            int row = wc * 64 + n * 16 + lrow;
            #pragma unroll
            for (int ks = 0; ks < 2; ++ks) {
                int off = row * 128 + (((ks * 4 + lhi) ^ (lrow & 7)) * 16);
                bfm[n][ks] = *(const bf16x8_t*)(Bb + off);
            }
        }
        #pragma unroll
        for (int m = 0; m < 4; ++m)
            #pragma unroll
            for (int n = 0; n < 4; ++n)
                #pragma unroll
                for (int ks = 0; ks < 2; ++ks)
                    acc[m][n] = __builtin_amdgcn_mfma_f32_16x16x32_bf16(
                        af[m][ks], bfm[n][ks], acc[m][n], 0, 0, 0);
        __syncthreads();
    }

    #pragma unroll
    for (int m = 0; m < 4; ++m) {
        int row = m0 + wr * 64 + m * 16 + lhi * 4;
        #pragma unroll
        for (int n = 0; n < 4; ++n) {
            int col = n0 + wc * 64 + n * 16 + lrow;
            if (col < VOCAB) {
                float bo = bout[col];
                #pragma unroll
                for (int q = 0; q < 4; ++q)
                    out[(size_t)(row + q) * VOCAB + col] = tanhf(acc[m][n][q] + bo);
            }
        }
    }
}

// ---------------------------------------------------------------------------
extern "C" void kernel_launch(void* const* d_in, const int* in_sizes, int n_in,
                              void* d_out, int out_size, void* d_ws, size_t ws_size,
                              hipStream_t stream)
{
    const int*   inputs = (const int*)  d_in[0];
    const float* hidden = (const float*)d_in[1];
    const float* emb    = (const float*)d_in[2];
    const float* Wr     = (const float*)d_in[3];
    const float* br     = (const float*)d_in[4];
    const float* Wz     = (const float*)d_in[5];
    const float* bz     = (const float*)d_in[6];
    const float* Wg     = (const float*)d_in[7];
    const float* bg     = (const float*)d_in[8];
    const float* Wout   = (const float*)d_in[9];
    const float* bout   = (const float*)d_in[10];
    float* out = (float*)d_out;

    const size_t BH = BATCH * HID;                 // 131072

    float* ws = (float*)d_ws;
    float* h0      = ws;                           // BH
    float* h1      = h0 + BH;                      // BH
    float* rmat0   = h1 + BH;                      // BH
    float* rmat1   = rmat0 + BH;                   // BH
    float* part_rz = rmat1 + BH;                   // 2*8*262144
    float* part_g  = part_rz + 2 * NSPLIT * (BATCH * 2 * HID);  // 2*8*131072
    float* xemb    = part_g + 2 * NSPLIT * (BATCH * HID);       // T*B*H
    ushort_t* h1bf = (ushort_t*)(xemb + (size_t)T_STEPS * BH);  // T*B*H bf16
    ushort_t* WT   = h1bf + (size_t)T_STEPS * BH;               // VPAD*H bf16

    init_h<<<(int)(BH + 255) / 256, 256, 0, stream>>>(hidden, h0, h1);
    gather_kernel<<<T_STEPS * BATCH, 256, 0, stream>>>(inputs, emb, xemb);
    woutT_kernel<<<dim3(VPAD / 32, HID / 32), 256, 0, stream>>>(Wout, WT);

    for (int s = 0; s <= T_STEPS; ++s) {
        int do0 = (s < T_STEPS) ? 1 : 0;
        int do1 = (s >= 1) ? 1 : 0;
        const float* xemb_t0 = xemb + (size_t)s * BH;
        agemm_s<<<dim3(64, NSPLIT, 2), 512, 0, stream>>>(
            xemb_t0, h0, h1, Wr, Wz, part_rz, do0, do1);
        aact_kernel<<<dim3(128, 2), 256, 0, stream>>>(
            part_rz, br, rmat0, rmat1, do0, do1);
        bgemm_s<<<dim3(32, NSPLIT, 2), 512, 0, stream>>>(
            xemb_t0, h0, h1, rmat0, rmat1, Wg, part_g, do0, do1);
        bact_kernel<<<dim3(128, 2), 256, 0, stream>>>(
            part_rz, part_g, bz, bg, h0, h1, h1bf, s - 1, do0, do1);
    }

    final_h<<<(int)(BH + 255) / 256, 256, 0, stream>>>(
        h0, h1, out + (size_t)T_STEPS * BATCH * VOCAB);

    logits_mfma_kernel<<<dim3(VPAD / 128, 8192 / 128), 256, 0, stream>>>(
        h1bf, WT, bout, out);
}

// Round 10
// 4326.444 us; speedup vs baseline: 2.9889x; 1.5889x over previous
//
#include <hip/hip_runtime.h>

#define T_STEPS 64
#define BATCH   128
#define HID     1024
#define VOCAB   10000
#define VPAD    10240
#define NSPLIT  8
#define KCHUNK  256

typedef unsigned short ushort_t;
typedef __attribute__((ext_vector_type(8))) short bf16x8_t;
typedef __attribute__((ext_vector_type(4))) float f32x4_t;

typedef const unsigned int __attribute__((address_space(1)))* gptr1_t;
typedef unsigned int __attribute__((address_space(3)))* lptr3_t;

#if defined(__has_builtin)
#if __has_builtin(__builtin_amdgcn_global_load_lds)
#define HAVE_GLL 1
#endif
#endif

__device__ inline unsigned short f2bf(float f) {
    unsigned int u = __float_as_uint(f);
    u += 0x7fffu + ((u >> 16) & 1u);
    return (unsigned short)(u >> 16);
}

// ---------------------------------------------------------------------------
__global__ void init_h(const float* __restrict__ hidden,
                       float* __restrict__ h0, float* __restrict__ h1)
{
    int i = blockIdx.x * blockDim.x + threadIdx.x;
    if (i < BATCH * HID) {
        h0[i] = hidden[i];
        h1[i] = hidden[BATCH * HID + i];
    }
}

__global__ void final_h(const float* __restrict__ h0, const float* __restrict__ h1,
                        float* __restrict__ out)
{
    int i = blockIdx.x * blockDim.x + threadIdx.x;
    if (i < BATCH * HID) {
        out[i] = h0[i];
        out[BATCH * HID + i] = h1[i];
    }
}

__global__ __launch_bounds__(256)
void gather_kernel(const int* __restrict__ ids, const float* __restrict__ emb,
                   float* __restrict__ xemb)
{
    const int row = blockIdx.x;
    const int c4 = threadIdx.x * 4;
    float4 v = *(const float4*)&emb[(size_t)ids[row] * HID + c4];
    *(float4*)&xemb[(size_t)row * HID + c4] = v;
}

__global__ __launch_bounds__(256)
void woutT_kernel(const float* __restrict__ Wout, ushort_t* __restrict__ WT)
{
    __shared__ float ld[32][33];
    const int v0 = blockIdx.x * 32, k0 = blockIdx.y * 32;
    const int r = threadIdx.x >> 3;
    const int c4 = (threadIdx.x & 7) * 4;
    #pragma unroll
    for (int q = 0; q < 4; ++q) {
        int v = v0 + c4 + q;
        float val = 0.0f;
        if (v < VOCAB) val = Wout[(size_t)(k0 + r) * VOCAB + v];
        ld[c4 + q][r] = val;
    }
    __syncthreads();
    ushort4 o;
    o.x = f2bf(ld[r][c4 + 0]);
    o.y = f2bf(ld[r][c4 + 1]);
    o.z = f2bf(ld[r][c4 + 2]);
    o.w = f2bf(ld[r][c4 + 3]);
    *(ushort4*)&WT[(size_t)(v0 + r) * HID + k0 + c4] = o;
}

// ---------------------------------------------------------------------------
// agemm_k: rz partial GEMM. 512 threads (8 waves), TM=128, TN=64, TK=64,
// KCHUNK=256 (NSPLIT=8 splits), grid (32, 8, 2).
// Staging via global_load_lds(16B); A source-swizzled (chunk ^= row&3) so the
// unpadded [128][64] A-reads are bank-conflict-free; B unswizzled (2-way max).
// Per-output FMA order: k ascending (canary 1.1063840e13 preserved).
// ---------------------------------------------------------------------------
__global__ __launch_bounds__(512)
void agemm_k(const float* __restrict__ xemb_t0,
             const float* __restrict__ h0, const float* __restrict__ h1,
             const float* __restrict__ Wr, const float* __restrict__ Wz,
             float* __restrict__ part_rz, int do0, int do1)
{
    const int layer = blockIdx.z;
    if (layer == 0 && !do0) return;
    if (layer == 1 && !do1) return;

    __shared__ float As[128 * 64];
    __shared__ float Bs[64 * 64];
    const int tid = threadIdx.x;
    const int w = tid >> 6;
    const int lane = tid & 63;
    const int lrow = lane >> 4;       // 0..3
    const int lchunk = lane & 15;     // 0..15
    const int tx = tid & 15;          // col group (4 cols)
    const int ty = tid >> 4;          // row base (0..31)
    const int j0 = blockIdx.x * 64;
    const int kbase = blockIdx.y * KCHUNK;

    const float* W = ((j0 < HID) ? Wr : Wz) + (size_t)layer * (2 * HID * HID);
    const int jc = j0 & (HID - 1);
    const float* A_lo = layer ? h0 : xemb_t0;
    const float* A_hi = layer ? h1 : h0;

    float acc[4][4] = {};

    for (int kt0 = 0; kt0 < KCHUNK; kt0 += 64) {
        const int kg0 = kbase + kt0;                  // uniform per tile
        const float* src = (kg0 < HID) ? A_lo : A_hi;
        const int kmod = kg0 & (HID - 1);
        if (kt0 > 0) __syncthreads();
        // stage A: 32 KB, 4 issues/wave; source chunk-swizzled
        #pragma unroll
        for (int ii = 0; ii < 4; ++ii) {
            int issue = w * 4 + ii;                   // 0..31
            int r = issue * 4 + lrow;                 // 0..127
            int gc = (lchunk ^ (r & 3)) * 4;
            const float* ga = src + (size_t)r * HID + kmod + gc;
#ifdef HAVE_GLL
            __builtin_amdgcn_global_load_lds((gptr1_t)(const void*)ga,
                (lptr3_t)(void*)(As + issue * 256), 16, 0, 0);
#else
            *(float4*)&As[issue * 256 + lane * 4] = *(const float4*)ga;
#endif
        }
        // stage B: 16 KB, 2 issues/wave
        #pragma unroll
        for (int ii = 0; ii < 2; ++ii) {
            int issue = w * 2 + ii;                   // 0..15
            int kr = issue * 4 + lrow;                // 0..63
            const float* gb = W + (size_t)(kg0 + kr) * HID + jc + lchunk * 4;
#ifdef HAVE_GLL
            __builtin_amdgcn_global_load_lds((gptr1_t)(const void*)gb,
                (lptr3_t)(void*)(Bs + issue * 256), 16, 0, 0);
#else
            *(float4*)&Bs[issue * 256 + lane * 4] = *(const float4*)gb;
#endif
        }
        __syncthreads();
        // compute: per thread 4 rows (ty+32i) x 4 cols (tx*4)
        #pragma unroll
        for (int kk = 0; kk < 64; kk += 4) {
            f32x4_t b[4];
            #pragma unroll
            for (int q = 0; q < 4; ++q)
                b[q] = *(const f32x4_t*)&Bs[(kk + q) * 64 + tx * 4];
            #pragma unroll
            for (int i = 0; i < 4; ++i) {
                int row = ty + i * 32;
                int cswz = (((kk >> 2) ^ (row & 3)) << 2);
                f32x4_t a = *(const f32x4_t*)&As[row * 64 + cswz];
                #pragma unroll
                for (int q = 0; q < 4; ++q) {
                    acc[i][0] += a[q] * b[q][0];
                    acc[i][1] += a[q] * b[q][1];
                    acc[i][2] += a[q] * b[q][2];
                    acc[i][3] += a[q] * b[q][3];
                }
            }
        }
    }

    float* dst = part_rz + (size_t)(layer * NSPLIT + blockIdx.y) * (BATCH * 2 * HID);
    #pragma unroll
    for (int i = 0; i < 4; ++i) {
        int row = ty + i * 32;
        float4 v;
        v.x = acc[i][0]; v.y = acc[i][1]; v.z = acc[i][2]; v.w = acc[i][3];
        *(float4*)&dst[(size_t)row * 2048 + j0 + tx * 4] = v;
    }
}

// ---------------------------------------------------------------------------
// aact: r = tanh(sum_splits part_rz[.., j<H] + br);  rh = r * h_old
// (rh precomputed so bgemm staging is a pure DMA copy)
// ---------------------------------------------------------------------------
__global__ __launch_bounds__(256)
void aact_kernel(const float* __restrict__ part_rz,
                 const float* __restrict__ br,
                 const float* __restrict__ h0, const float* __restrict__ h1,
                 float* __restrict__ rh0, float* __restrict__ rh1,
                 int do0, int do1)
{
    const int layer = blockIdx.y;
    if (layer == 0 && !do0) return;
    if (layer == 1 && !do1) return;
    const int idx4 = (blockIdx.x * 256 + threadIdx.x) * 4;
    const int b = idx4 >> 10, j = idx4 & (HID - 1);
    const float* p = part_rz + (size_t)layer * NSPLIT * (BATCH * 2 * HID)
                   + (size_t)b * 2048 + j;
    float4 s = {0.f, 0.f, 0.f, 0.f};
    #pragma unroll
    for (int sp = 0; sp < NSPLIT; ++sp) {
        float4 v = *(const float4*)&p[(size_t)sp * (BATCH * 2 * HID)];
        s.x += v.x; s.y += v.y; s.z += v.z; s.w += v.w;
    }
    float4 bb = *(const float4*)&br[layer * HID + j];
    float4 hv = *(const float4*)&(layer ? h1 : h0)[idx4];
    float4 rh;
    rh.x = tanhf(s.x + bb.x) * hv.x;
    rh.y = tanhf(s.y + bb.y) * hv.y;
    rh.z = tanhf(s.z + bb.z) * hv.z;
    rh.w = tanhf(s.w + bb.w) * hv.w;
    *(float4*)&(layer ? rh1 : rh0)[idx4] = rh;
}

// ---------------------------------------------------------------------------
// bgemm_k: g partial GEMM. 512 threads, TM=128, TN=32, TK=64, grid (32,8,2).
//   A2 (layer0) = k<H ? xemb : rh0 ; (layer1) = k<H ? h0 : rh1  (pure copies)
// Same staging scheme; per thread 4 rows x 2 cols.
// ---------------------------------------------------------------------------
__global__ __launch_bounds__(512)
void bgemm_k(const float* __restrict__ xemb_t0,
             const float* __restrict__ h0, const float* __restrict__ h1,
             const float* __restrict__ rh0, const float* __restrict__ rh1,
             const float* __restrict__ Wg,
             float* __restrict__ part_g, int do0, int do1)
{
    const int layer = blockIdx.z;
    if (layer == 0 && !do0) return;
    if (layer == 1 && !do1) return;

    __shared__ float As[128 * 64];
    __shared__ float Bs[64 * 32];
    const int tid = threadIdx.x;
    const int w = tid >> 6;
    const int lane = tid & 63;
    const int lrow = lane >> 4;
    const int lchunk = lane & 15;
    const int tx = tid & 15;          // col group (2 cols)
    const int ty = tid >> 4;          // 0..31
    const int j0 = blockIdx.x * 32;
    const int kbase = blockIdx.y * KCHUNK;

    const float* W = Wg + (size_t)layer * (2 * HID * HID);
    const float* A_lo = layer ? h0 : xemb_t0;
    const float* A_hi = layer ? rh1 : rh0;

    float acc[4][2] = {};

    for (int kt0 = 0; kt0 < KCHUNK; kt0 += 64) {
        const int kg0 = kbase + kt0;
        const float* src = (kg0 < HID) ? A_lo : A_hi;
        const int kmod = kg0 & (HID - 1);
        if (kt0 > 0) __syncthreads();
        #pragma unroll
        for (int ii = 0; ii < 4; ++ii) {
            int issue = w * 4 + ii;
            int r = issue * 4 + lrow;
            int gc = (lchunk ^ (r & 3)) * 4;
            const float* ga = src + (size_t)r * HID + kmod + gc;
#ifdef HAVE_GLL
            __builtin_amdgcn_global_load_lds((gptr1_t)(const void*)ga,
                (lptr3_t)(void*)(As + issue * 256), 16, 0, 0);
#else
            *(float4*)&As[issue * 256 + lane * 4] = *(const float4*)ga;
#endif
        }
        // stage B: 8 KB, 1 issue/wave; issue covers 8 k-rows x 32 cols
        {
            int kr = w * 8 + (lane >> 3);             // 0..63
            const float* gb = W + (size_t)(kg0 + kr) * HID + j0 + (lane & 7) * 4;
#ifdef HAVE_GLL
            __builtin_amdgcn_global_load_lds((gptr1_t)(const void*)gb,
                (lptr3_t)(void*)(Bs + w * 256), 16, 0, 0);
#else
            *(float4*)&Bs[w * 256 + lane * 4] = *(const float4*)gb;
#endif
        }
        __syncthreads();
        #pragma unroll
        for (int kk = 0; kk < 64; kk += 4) {
            float2 b[4];
            #pragma unroll
            for (int q = 0; q < 4; ++q)
                b[q] = *(const float2*)&Bs[(kk + q) * 32 + tx * 2];
            #pragma unroll
            for (int i = 0; i < 4; ++i) {
                int row = ty + i * 32;
                int cswz = (((kk >> 2) ^ (row & 3)) << 2);
                f32x4_t a = *(const f32x4_t*)&As[row * 64 + cswz];
                #pragma unroll
                for (int q = 0; q < 4; ++q) {
                    acc[i][0] += a[q] * b[q].x;
                    acc[i][1] += a[q] * b[q].y;
                }
            }
        }
    }

    float* dst = part_g + (size_t)(layer * NSPLIT + blockIdx.y) * (BATCH * HID);
    #pragma unroll
    for (int i = 0; i < 4; ++i) {
        int row = ty + i * 32;
        float2 v;
        v.x = acc[i][0]; v.y = acc[i][1];
        *(float2*)&dst[(size_t)row * HID + j0 + tx * 2] = v;
    }
}

// ---------------------------------------------------------------------------
// bact: z/g reduction + tanh + h update (unchanged numerics)
// ---------------------------------------------------------------------------
__global__ __launch_bounds__(256)
void bact_kernel(const float* __restrict__ part_rz, const float* __restrict__ part_g,
                 const float* __restrict__ bz, const float* __restrict__ bg,
                 float* __restrict__ h0, float* __restrict__ h1,
                 ushort_t* __restrict__ h1bf, int t1, int do0, int do1)
{
    const int layer = blockIdx.y;
    if (layer == 0 && !do0) return;
    if (layer == 1 && !do1) return;
    const int idx4 = (blockIdx.x * 256 + threadIdx.x) * 4;
    const int b = idx4 >> 10, j = idx4 & (HID - 1);

    const float* pz = part_rz + (size_t)layer * NSPLIT * (BATCH * 2 * HID)
                    + (size_t)b * 2048 + HID + j;
    float4 sz = {0.f, 0.f, 0.f, 0.f};
    #pragma unroll
    for (int sp = 0; sp < NSPLIT; ++sp) {
        float4 v = *(const float4*)&pz[(size_t)sp * (BATCH * 2 * HID)];
        sz.x += v.x; sz.y += v.y; sz.z += v.z; sz.w += v.w;
    }
    float4 bzv = *(const float4*)&bz[layer * HID + j];
    float4 z;
    z.x = tanhf(sz.x + bzv.x); z.y = tanhf(sz.y + bzv.y);
    z.z = tanhf(sz.z + bzv.z); z.w = tanhf(sz.w + bzv.w);

    const float* pg = part_g + (size_t)layer * NSPLIT * (BATCH * HID) + idx4;
    float4 sg = {0.f, 0.f, 0.f, 0.f};
    #pragma unroll
    for (int sp = 0; sp < NSPLIT; ++sp) {
        float4 v = *(const float4*)&pg[(size_t)sp * (BATCH * HID)];
        sg.x += v.x; sg.y += v.y; sg.z += v.z; sg.w += v.w;
    }
    float4 bgv = *(const float4*)&bg[layer * HID + j];
    float4 g;
    g.x = tanhf(sg.x + bgv.x); g.y = tanhf(sg.y + bgv.y);
    g.z = tanhf(sg.z + bgv.z); g.w = tanhf(sg.w + bgv.w);

    float* h = layer ? h1 : h0;
    float4 hv = *(const float4*)&h[idx4];
    float4 hn;
    hn.x = (1.0f - z.x) * hv.x + z.x * g.x;
    hn.y = (1.0f - z.y) * hv.y + z.y * g.y;
    hn.z = (1.0f - z.z) * hv.z + z.z * g.z;
    hn.w = (1.0f - z.w) * hv.w + z.w * g.w;
    *(float4*)&h[idx4] = hn;

    if (layer == 1) {
        ushort4 o;
        o.x = f2bf(hn.x); o.y = f2bf(hn.y); o.z = f2bf(hn.z); o.w = f2bf(hn.w);
        *(ushort4*)&h1bf[(size_t)t1 * (BATCH * HID) + idx4] = o;
    }
}

// ---------------------------------------------------------------------------
// Logits MFMA GEMM (unchanged)
// ---------------------------------------------------------------------------
__global__ __launch_bounds__(256)
void logits_mfma_kernel(const ushort_t* __restrict__ Abf,
                        const ushort_t* __restrict__ BT,
                        const float* __restrict__ bout,
                        float* __restrict__ out)
{
    __shared__ ushort_t As[128 * 64];
    __shared__ ushort_t Bs[128 * 64];
    const int tid = threadIdx.x;
    const int wave = tid >> 6, lane = tid & 63;
    const int m0 = blockIdx.y * 128, n0 = blockIdx.x * 128;
    const int wr = wave >> 1, wc = wave & 1;

    const int srow = lane >> 3;
    const int sch = (lane & 7) ^ (srow & 7);
    const int lrow = lane & 15, lhi = lane >> 4;

    f32x4_t acc[4][4] = {};

    for (int k0 = 0; k0 < HID; k0 += 64) {
        #pragma unroll
        for (int i = 0; i < 4; ++i) {
            int issue = wave * 4 + i;
            int row = issue * 8 + srow;
            const ushort_t* ga = Abf + (size_t)(m0 + row) * HID + k0 + sch * 8;
            const ushort_t* gb = BT + (size_t)(n0 + row) * HID + k0 + sch * 8;
#ifdef HAVE_GLL
            __builtin_amdgcn_global_load_lds((gptr1_t)(const void*)ga,
                                             (lptr3_t)(void*)(As + issue * 512), 16, 0, 0);
            __builtin_amdgcn_global_load_lds((gptr1_t)(const void*)gb,
                                             (lptr3_t)(void*)(Bs + issue * 512), 16, 0, 0);
#else
            *(bf16x8_t*)(As + issue * 512 + lane * 8) = *(const bf16x8_t*)ga;
            *(bf16x8_t*)(Bs + issue * 512 + lane * 8) = *(const bf16x8_t*)gb;
#endif
        }
        __syncthreads();

        bf16x8_t af[4][2], bfm[4][2];
        const char* Ab = (const char*)As;
        const char* Bb = (const char*)Bs;
        #pragma unroll
        for (int m = 0; m < 4; ++m) {
            int row = wr * 64 + m * 16 + lrow;
            #pragma unroll
            for (int ks = 0; ks < 2; ++ks) {
                int off = row * 128 + (((ks * 4 + lhi) ^ (lrow & 7)) * 16);
                af[m][ks] = *(const bf16x8_t*)(Ab + off);
            }
        }
        #pragma unroll
        for (int n = 0; n < 4; ++n) {
            int row = wc * 64 + n * 16 + lrow;
            #pragma unroll
            for (int ks = 0; ks < 2; ++ks) {
                int off = row * 128 + (((ks * 4 + lhi) ^ (lrow & 7)) * 16);
                bfm[n][ks] = *(const bf16x8_t*)(Bb + off);
            }
        }
        #pragma unroll
        for (int m = 0; m < 4; ++m)
            #pragma unroll
            for (int n = 0; n < 4; ++n)
                #pragma unroll
                for (int ks = 0; ks < 2; ++ks)
                    acc[m][n] = __builtin_amdgcn_mfma_f32_16x16x32_bf16(
                        af[m][ks], bfm[n][ks], acc[m][n], 0, 0, 0);
        __syncthreads();
    }

    #pragma unroll
    for (int m = 0; m < 4; ++m) {
        int row = m0 + wr * 64 + m * 16 + lhi * 4;
        #pragma unroll
        for (int n = 0; n < 4; ++n) {
            int col = n0 + wc * 64 + n * 16 + lrow;
            if (col < VOCAB) {
                float bo = bout[col];
                #pragma unroll
                for (int q = 0; q < 4; ++q)
                    out[(size_t)(row + q) * VOCAB + col] = tanhf(acc[m][n][q] + bo);
            }
        }
    }
}

// ---------------------------------------------------------------------------
extern "C" void kernel_launch(void* const* d_in, const int* in_sizes, int n_in,
                              void* d_out, int out_size, void* d_ws, size_t ws_size,
                              hipStream_t stream)
{
    const int*   inputs = (const int*)  d_in[0];
    const float* hidden = (const float*)d_in[1];
    const float* emb    = (const float*)d_in[2];
    const float* Wr     = (const float*)d_in[3];
    const float* br     = (const float*)d_in[4];
    const float* Wz     = (const float*)d_in[5];
    const float* bz     = (const float*)d_in[6];
    const float* Wg     = (const float*)d_in[7];
    const float* bg     = (const float*)d_in[8];
    const float* Wout   = (const float*)d_in[9];
    const float* bout   = (const float*)d_in[10];
    float* out = (float*)d_out;

    const size_t BH = BATCH * HID;                 // 131072

    float* ws = (float*)d_ws;
    float* h0      = ws;                           // BH
    float* h1      = h0 + BH;                      // BH
    float* rh0     = h1 + BH;                      // BH
    float* rh1     = rh0 + BH;                     // BH
    float* part_rz = rh1 + BH;                     // 2*8*262144
    float* part_g  = part_rz + 2 * NSPLIT * (BATCH * 2 * HID);  // 2*8*131072
    float* xemb    = part_g + 2 * NSPLIT * (BATCH * HID);       // T*B*H
    ushort_t* h1bf = (ushort_t*)(xemb + (size_t)T_STEPS * BH);  // T*B*H bf16
    ushort_t* WT   = h1bf + (size_t)T_STEPS * BH;               // VPAD*H bf16

    init_h<<<(int)(BH + 255) / 256, 256, 0, stream>>>(hidden, h0, h1);
    gather_kernel<<<T_STEPS * BATCH, 256, 0, stream>>>(inputs, emb, xemb);
    woutT_kernel<<<dim3(VPAD / 32, HID / 32), 256, 0, stream>>>(Wout, WT);

    for (int s = 0; s <= T_STEPS; ++s) {
        int do0 = (s < T_STEPS) ? 1 : 0;
        int do1 = (s >= 1) ? 1 : 0;
        const float* xemb_t0 = xemb + (size_t)s * BH;
        agemm_k<<<dim3(32, NSPLIT, 2), 512, 0, stream>>>(
            xemb_t0, h0, h1, Wr, Wz, part_rz, do0, do1);
        aact_kernel<<<dim3(128, 2), 256, 0, stream>>>(
            part_rz, br, h0, h1, rh0, rh1, do0, do1);
        bgemm_k<<<dim3(32, NSPLIT, 2), 512, 0, stream>>>(
            xemb_t0, h0, h1, rh0, rh1, Wg, part_g, do0, do1);
        bact_kernel<<<dim3(128, 2), 256, 0, stream>>>(
            part_rz, part_g, bz, bg, h0, h1, h1bf, s - 1, do0, do1);
    }

    final_h<<<(int)(BH + 255) / 256, 256, 0, stream>>>(
        h0, h1, out + (size_t)T_STEPS * BATCH * VOCAB);

    logits_mfma_kernel<<<dim3(VPAD / 128, 8192 / 128), 256, 0, stream>>>(
        h1bf, WT, bout, out);
}